// Round 9
// baseline (887.847 us; speedup 1.0000x reference)
//
#include <hip/hip_runtime.h>

#define N_NODES 100000
#define N_EDGES 1600000
#define F_IN    128
#define HID     64
#define N_CLASS 40
#define NEG_SLOPE 0.2f
#define ET (N_EDGES + N_NODES)          // 1,700,000
#define ROW_BLOCKS ((N_NODES + 63) / 64)

// ---- 2-level radix partition geometry ----
#define NCB   7
#define CAP1  294912
#define BPC   144
#define NFB   782
#define CAPF  2624
#define NT1   ((ET + 2047) / 2048)

typedef __attribute__((ext_vector_type(8))) short bf16x8;
typedef __attribute__((ext_vector_type(4))) float f32x4;

__device__ __forceinline__ unsigned int f2bf(float f) {  // fp32 -> bf16 (RNE)
    unsigned int u = __float_as_uint(f);
    return (u + 0x7fffu + ((u >> 16) & 1u)) >> 16;
}

// ---------------------------------------------------------------------------
// Weight prep: bf16 transposed [n][k] so MFMA B-frags are contiguous 16 B.
// W2 padded to 48 output cols (zeros).
// ---------------------------------------------------------------------------
__global__ __launch_bounds__(256) void k_prepw(const float* __restrict__ W1,
        const float* __restrict__ Wc0, const float* __restrict__ Wc1,
        const float* __restrict__ W2,
        unsigned short* __restrict__ Wt1, unsigned short* __restrict__ Wtc0,
        unsigned short* __restrict__ Wtc1, unsigned short* __restrict__ W2t) {
    int t = threadIdx.x;
    for (int i = t; i < F_IN * HID; i += 256) {
        int k = i >> 6, n = i & 63;
        Wt1[n * F_IN + k] = (unsigned short)f2bf(W1[i]);
    }
    for (int i = t; i < HID * HID; i += 256) {
        int k = i >> 6, n = i & 63;
        Wtc0[n * HID + k] = (unsigned short)f2bf(Wc0[i]);
        Wtc1[n * HID + k] = (unsigned short)f2bf(Wc1[i]);
    }
    for (int i = t; i < 48 * HID; i += 256) {
        int n = i >> 6, k = i & 63;
        W2t[n * HID + k] = (n < N_CLASS)
            ? (unsigned short)f2bf(W2[k * N_CLASS + n]) : (unsigned short)0;
    }
}

// ---------------------------------------------------------------------------
// h0 = relu(x @ W1 + b1) via MFMA 16x16x32 bf16. Block = 4 waves = 64 rows.
// ---------------------------------------------------------------------------
__global__ __launch_bounds__(256) void k_lin1(const float* __restrict__ x,
        const unsigned short* __restrict__ Wt1, const float* __restrict__ b1,
        unsigned short* __restrict__ h0b) {
    __shared__ float xs[4][16 * 68];
    int t = threadIdx.x;
    int lane = t & 63, w = t >> 6;
    int quad = lane >> 4, lr = lane & 15;
    int rowg0 = blockIdx.x * 64 + w * 16;

    bf16x8 bfr[4][4];                       // [kc][nt]
    #pragma unroll
    for (int kc = 0; kc < 4; ++kc)
        #pragma unroll
        for (int nt = 0; nt < 4; ++nt)
            bfr[kc][nt] = *(const bf16x8*)(Wt1 + (nt * 16 + lr) * F_IN
                                           + kc * 32 + quad * 8);
    f32x4 zero = {0.f, 0.f, 0.f, 0.f};
    f32x4 acc[4] = {zero, zero, zero, zero};

    int arow = rowg0 + lr; if (arow >= N_NODES) arow = N_NODES - 1;
    const float* ab = x + (size_t)arow * F_IN;
    #pragma unroll
    for (int kc = 0; kc < 4; ++kc) {
        const float* ap = ab + kc * 32 + quad * 8;
        float4 a0 = *(const float4*)ap;
        float4 a1 = *(const float4*)(ap + 4);
        union { bf16x8 v; unsigned int u[4]; } af;
        af.u[0] = f2bf(a0.x) | (f2bf(a0.y) << 16);
        af.u[1] = f2bf(a0.z) | (f2bf(a0.w) << 16);
        af.u[2] = f2bf(a1.x) | (f2bf(a1.y) << 16);
        af.u[3] = f2bf(a1.z) | (f2bf(a1.w) << 16);
        #pragma unroll
        for (int nt = 0; nt < 4; ++nt)
            acc[nt] = __builtin_amdgcn_mfma_f32_16x16x32_bf16(
                          af.v, bfr[kc][nt], acc[nt], 0, 0, 0);
    }
    #pragma unroll
    for (int nt = 0; nt < 4; ++nt) {
        float bv = b1[nt * 16 + lr];
        #pragma unroll
        for (int reg = 0; reg < 4; ++reg)
            xs[w][(quad * 4 + reg) * 68 + nt * 16 + lr] =
                fmaxf(acc[nt][reg] + bv, 0.f);
    }
    __syncthreads();
    #pragma unroll
    for (int j = 0; j < 2; ++j) {
        int task = j * 64 + lane;           // 16 rows x 8 col-groups
        int r = task >> 3, g = task & 7;
        int grow = blockIdx.x * 64 + w * 16 + r;
        if (grow < N_NODES) {
            const float* p = xs[w] + r * 68 + g * 8;
            uint4 u;
            u.x = f2bf(p[0]) | (f2bf(p[1]) << 16);
            u.y = f2bf(p[2]) | (f2bf(p[3]) << 16);
            u.z = f2bf(p[4]) | (f2bf(p[5]) << 16);
            u.w = f2bf(p[6]) | (f2bf(p[7]) << 16);
            *(uint4*)(h0b + (size_t)grow * HID + g * 8) = u;
        }
    }
}

// ---------------------------------------------------------------------------
// h = hin @ Wc (MFMA, bf16 in/out) ; as_ = h@att_src ; ad_ = h@att_dst.
// ---------------------------------------------------------------------------
__global__ __launch_bounds__(256) void k_gemm_att(
        const unsigned short* __restrict__ hin,
        const unsigned short* __restrict__ Wt,
        const float* __restrict__ att_s, const float* __restrict__ att_d,
        unsigned short* __restrict__ hb, float* __restrict__ as_,
        float* __restrict__ ad_) {
    __shared__ float xs[4][16 * 68];
    int t = threadIdx.x;
    int lane = t & 63, w = t >> 6;
    int quad = lane >> 4, lr = lane & 15;
    int rowg0 = blockIdx.x * 64 + w * 16;

    bf16x8 bfr[2][4];
    #pragma unroll
    for (int kc = 0; kc < 2; ++kc)
        #pragma unroll
        for (int nt = 0; nt < 4; ++nt)
            bfr[kc][nt] = *(const bf16x8*)(Wt + (nt * 16 + lr) * HID
                                           + kc * 32 + quad * 8);
    f32x4 zero = {0.f, 0.f, 0.f, 0.f};
    f32x4 acc[4] = {zero, zero, zero, zero};

    int arow = rowg0 + lr; if (arow >= N_NODES) arow = N_NODES - 1;
    #pragma unroll
    for (int kc = 0; kc < 2; ++kc) {
        bf16x8 af = *(const bf16x8*)(hin + (size_t)arow * HID
                                     + kc * 32 + quad * 8);
        #pragma unroll
        for (int nt = 0; nt < 4; ++nt)
            acc[nt] = __builtin_amdgcn_mfma_f32_16x16x32_bf16(
                          af, bfr[kc][nt], acc[nt], 0, 0, 0);
    }
    float asv[4], adv[4];
    #pragma unroll
    for (int nt = 0; nt < 4; ++nt) {
        asv[nt] = att_s[nt * 16 + lr];
        adv[nt] = att_d[nt * 16 + lr];
    }
    #pragma unroll
    for (int reg = 0; reg < 4; ++reg) {
        float p1 = acc[0][reg] * asv[0] + acc[1][reg] * asv[1]
                 + acc[2][reg] * asv[2] + acc[3][reg] * asv[3];
        float p2 = acc[0][reg] * adv[0] + acc[1][reg] * adv[1]
                 + acc[2][reg] * adv[2] + acc[3][reg] * adv[3];
        #pragma unroll
        for (int off = 1; off < 16; off <<= 1) {
            p1 += __shfl_xor(p1, off, 64);
            p2 += __shfl_xor(p2, off, 64);
        }
        if (lr == 0) {
            int grow = rowg0 + quad * 4 + reg;
            if (grow < N_NODES) { as_[grow] = p1; ad_[grow] = p2; }
        }
    }
    #pragma unroll
    for (int nt = 0; nt < 4; ++nt)
        #pragma unroll
        for (int reg = 0; reg < 4; ++reg)
            xs[w][(quad * 4 + reg) * 68 + nt * 16 + lr] = acc[nt][reg];
    __syncthreads();
    #pragma unroll
    for (int j = 0; j < 2; ++j) {
        int task = j * 64 + lane;
        int r = task >> 3, g = task & 7;
        int grow = blockIdx.x * 64 + w * 16 + r;
        if (grow < N_NODES) {
            const float* p = xs[w] + r * 68 + g * 8;
            uint4 u;
            u.x = f2bf(p[0]) | (f2bf(p[1]) << 16);
            u.y = f2bf(p[2]) | (f2bf(p[3]) << 16);
            u.z = f2bf(p[4]) | (f2bf(p[5]) << 16);
            u.w = f2bf(p[6]) | (f2bf(p[7]) << 16);
            *(uint4*)(hb + (size_t)grow * HID + g * 8) = u;
        }
    }
}

// ---------------------------------------------------------------------------
// Partition level 1: edges -> 7 coarse buckets (dst>>14).
// ---------------------------------------------------------------------------
__global__ __launch_bounds__(256) void k_part1(const int* __restrict__ ei,
        int* __restrict__ tail1, int2* __restrict__ buf1) {
    __shared__ int2 eb[2048];
    __shared__ int hist[NCB], lbase[NCB], loff[NCB], goff[NCB];
    int t = threadIdx.x;
    int tileBase = blockIdx.x * 2048;
    int total = ET - tileBase; if (total > 2048) total = 2048;
    if (t < NCB) hist[t] = 0;
    __syncthreads();

    int sr[8], dr[8];
    #pragma unroll
    for (int r = 0; r < 8; ++r) {
        int i = tileBase + r * 256 + t;
        int s = -1, d = -1;
        if (i < ET) {
            if (i < N_EDGES) { s = ei[i]; d = ei[N_EDGES + i]; }
            else             { s = d = i - N_EDGES; }
            atomicAdd(&hist[d >> 14], 1);
        }
        sr[r] = s; dr[r] = d;
    }
    __syncthreads();
    if (t == 0) {
        int run = 0;
        for (int b = 0; b < NCB; ++b) { lbase[b] = run; loff[b] = 0; run += hist[b]; }
    }
    __syncthreads();
    if (t < NCB && hist[t] > 0) goff[t] = atomicAdd(&tail1[t], hist[t]);
    #pragma unroll
    for (int r = 0; r < 8; ++r) {
        if (dr[r] >= 0) {
            int b = dr[r] >> 14;
            int p = lbase[b] + atomicAdd(&loff[b], 1);
            eb[p] = make_int2(sr[r], dr[r]);
        }
    }
    __syncthreads();
    for (int j = t; j < total; j += 256) {
        int2 e = eb[j];
        int b = e.y >> 14;
        buf1[(size_t)b * CAP1 + goff[b] + (j - lbase[b])] = e;
    }
}

// ---------------------------------------------------------------------------
// Partition level 2: coarse bucket -> 128 fine buckets (128-dst ranges).
// ---------------------------------------------------------------------------
__global__ __launch_bounds__(256) void k_part2(const int2* __restrict__ buf1,
        const int* __restrict__ tail1, int* __restrict__ fcnt,
        int2* __restrict__ buf2) {
    __shared__ int2 eb[2048];
    __shared__ int hist[128], lbase[128], loff[128], goff[128], sc[128];
    int t = threadIdx.x;
    int cb   = blockIdx.x / BPC;
    int tile = blockIdx.x % BPC;
    int n1 = tail1[cb];
    int base = tile * 2048;
    if (base >= n1) return;
    int total = n1 - base; if (total > 2048) total = 2048;
    if (t < 128) hist[t] = 0;
    __syncthreads();

    int sr[8], dr[8];
    #pragma unroll
    for (int r = 0; r < 8; ++r) {
        int i = base + r * 256 + t;
        int s = -1, d = -1;
        if (i < n1) {
            int2 e = buf1[(size_t)cb * CAP1 + i];
            s = e.x; d = e.y;
            atomicAdd(&hist[(d >> 7) & 127], 1);
        }
        sr[r] = s; dr[r] = d;
    }
    __syncthreads();
    if (t < 128) sc[t] = hist[t];
    __syncthreads();
    for (int off = 1; off < 128; off <<= 1) {
        int u = (t < 128 && t >= off) ? sc[t - off] : 0;
        __syncthreads();
        if (t < 128) sc[t] += u;
        __syncthreads();
    }
    if (t < 128) { lbase[t] = sc[t] - hist[t]; loff[t] = 0; }
    __syncthreads();
    if (t < 128 && hist[t] > 0)
        goff[t] = atomicAdd(&fcnt[cb * 128 + t], hist[t]);
    #pragma unroll
    for (int r = 0; r < 8; ++r) {
        if (dr[r] >= 0) {
            int f = (dr[r] >> 7) & 127;
            int p = lbase[f] + atomicAdd(&loff[f], 1);
            eb[p] = make_int2(sr[r], dr[r]);
        }
    }
    __syncthreads();
    for (int j = t; j < total; j += 256) {
        int2 e = eb[j];
        int f = (e.y >> 7) & 127;
        buf2[(size_t)(e.y >> 7) * CAPF + goff[f] + (j - lbase[f])] = e;
    }
}

// ---------------------------------------------------------------------------
__global__ __launch_bounds__(1024) void k_fscan(const int* __restrict__ fcnt,
        int* __restrict__ fbase, int* __restrict__ rowptr) {
    __shared__ int s[1024];
    int t = threadIdx.x;
    int v = (t < NFB) ? fcnt[t] : 0;
    s[t] = v;
    __syncthreads();
    for (int off = 1; off < 1024; off <<= 1) {
        int u = (t >= off) ? s[t - off] : 0;
        __syncthreads();
        s[t] += u;
        __syncthreads();
    }
    if (t < NFB) fbase[t] = s[t] - v;
    if (t == 0) rowptr[N_NODES] = ET;
}

// ---------------------------------------------------------------------------
// Partition level 3: fine bucket -> exact per-node CSR.
// ---------------------------------------------------------------------------
__global__ __launch_bounds__(256) void k_part3(const int2* __restrict__ buf2,
        const int* __restrict__ fcnt, const int* __restrict__ fbase,
        int* __restrict__ rowptr, int* __restrict__ col) {
    __shared__ int2 eb[CAPF];
    __shared__ int cs[CAPF];
    __shared__ int hist[128], lbase[128], loff[128], sc[128];
    int t = threadIdx.x;
    int fb = blockIdx.x;
    int nF = fcnt[fb];
    int gb = fbase[fb];
    int dbase = fb * 128;
    if (t < 128) hist[t] = 0;
    __syncthreads();
    for (int j = t; j < nF; j += 256) {
        int2 e = buf2[(size_t)fb * CAPF + j];
        eb[j] = e;
        atomicAdd(&hist[e.y - dbase], 1);
    }
    __syncthreads();
    if (t < 128) sc[t] = hist[t];
    __syncthreads();
    for (int off = 1; off < 128; off <<= 1) {
        int u = (t < 128 && t >= off) ? sc[t - off] : 0;
        __syncthreads();
        if (t < 128) sc[t] += u;
        __syncthreads();
    }
    if (t < 128) { lbase[t] = sc[t] - hist[t]; loff[t] = 0; }
    __syncthreads();
    if (t < 128 && dbase + t < N_NODES) rowptr[dbase + t] = gb + lbase[t];
    for (int j = t; j < nF; j += 256) {
        int2 e = eb[j];
        int r = e.y - dbase;
        int p = lbase[r] + atomicAdd(&loff[r], 1);
        cs[p] = e.x;
    }
    __syncthreads();
    for (int j = t; j < nF; j += 256) col[gb + j] = cs[j];
}

// ---------------------------------------------------------------------------
// Degree bucket-sort: nodes ordered by degree so the 8 dsts sharing a wave in
// k_gat_agg have near-equal degree (lockstep groups, no divergence waste).
// ---------------------------------------------------------------------------
__global__ __launch_bounds__(256) void k_dhist(const int* __restrict__ rowptr,
        int* __restrict__ dhist) {
    int i = blockIdx.x * 256 + threadIdx.x;
    if (i >= N_NODES) return;
    int deg = rowptr[i + 1] - rowptr[i];
    if (deg > 63) deg = 63;
    atomicAdd(&dhist[deg], 1);
}

__global__ __launch_bounds__(64) void k_dscan(const int* __restrict__ dhist,
        int* __restrict__ dbase) {
    int t = threadIdx.x;
    int v = dhist[t];
    int s = v;
    #pragma unroll
    for (int off = 1; off < 64; off <<= 1) {
        int u = __shfl_up(s, off, 64);
        if (t >= off) s += u;
    }
    dbase[t] = s - v;   // exclusive
}

__global__ __launch_bounds__(256) void k_dscatter(const int* __restrict__ rowptr,
        int* __restrict__ dbase, int* __restrict__ nodeord) {
    int i = blockIdx.x * 256 + threadIdx.x;
    if (i >= N_NODES) return;
    int deg = rowptr[i + 1] - rowptr[i];
    if (deg > 63) deg = 63;
    int pos = atomicAdd(&dbase[deg], 1);
    nodeord[pos] = i;
}

// ---------------------------------------------------------------------------
// Fused GAT aggregate: 8 lanes per dst, 8 dsts per wave (degree-sorted so
// groups stay in lockstep). Lane holds 8 channels; 8 lanes x uint4 = the full
// 64-ch bf16 row per gather -> accumulators are complete, NO cross-lane
// reduce. j-loop compile-time unrolled 8 (8 gathers in flight). Output bf16.
// ---------------------------------------------------------------------------
template <bool RELU>
__global__ __launch_bounds__(256) void k_gat_agg(const int* __restrict__ rowptr,
        const int* __restrict__ col, const unsigned short* __restrict__ hb,
        const float* __restrict__ as_, const float* __restrict__ ad_,
        const float* __restrict__ bias, const int* __restrict__ nodeord,
        unsigned short* __restrict__ outb) {
    int t = threadIdx.x;
    int lane = t & 63;
    int wid = blockIdx.x * 4 + (t >> 6);
    int l8 = lane & 7;
    int ch = l8 * 8;
    int d = nodeord[wid * 8 + (lane >> 3)];
    int beg = rowptr[d];
    int deg = rowptr[d + 1] - beg;
    float add = ad_[d];
    int degw = deg;
    degw = max(degw, __shfl_xor(degw, 8, 64));
    degw = max(degw, __shfl_xor(degw, 16, 64));
    degw = max(degw, __shfl_xor(degw, 32, 64));

    float a0=0.f,a1=0.f,a2=0.f,a3=0.f,a4=0.f,a5=0.f,a6=0.f,a7=0.f,den=0.f;
    const unsigned short* hch = hb + ch;
    for (int c = 0; c < degw; c += 8) {
        int idx = c + l8;
        int sj = 0; float wj = 0.f;
        if (idx < deg) {
            sj = col[beg + idx];
            float e = as_[sj] + add;
            e = (e > 0.f) ? e : NEG_SLOPE * e;
            wj = __expf(e);
        }
        #pragma unroll
        for (int j = 0; j < 8; ++j) {
            int sl = (lane & 56) | j;
            int   s  = __shfl(sj, sl, 64);
            float w0 = __shfl(wj, sl, 64);   // 0 for padded slots
            den += w0;
            uint4 hv = *(const uint4*)(hch + (size_t)s * HID);
            a0 = fmaf(w0, __uint_as_float(hv.x << 16),         a0);
            a1 = fmaf(w0, __uint_as_float(hv.x & 0xffff0000u), a1);
            a2 = fmaf(w0, __uint_as_float(hv.y << 16),         a2);
            a3 = fmaf(w0, __uint_as_float(hv.y & 0xffff0000u), a3);
            a4 = fmaf(w0, __uint_as_float(hv.z << 16),         a4);
            a5 = fmaf(w0, __uint_as_float(hv.z & 0xffff0000u), a5);
            a6 = fmaf(w0, __uint_as_float(hv.w << 16),         a6);
            a7 = fmaf(w0, __uint_as_float(hv.w & 0xffff0000u), a7);
        }
    }
    float inv = 1.f / (den + 1e-16f);
    float4 bA = *(const float4*)(bias + ch);
    float4 bB = *(const float4*)(bias + ch + 4);
    float o0 = fmaf(a0, inv, bA.x), o1 = fmaf(a1, inv, bA.y);
    float o2 = fmaf(a2, inv, bA.z), o3 = fmaf(a3, inv, bA.w);
    float o4 = fmaf(a4, inv, bB.x), o5 = fmaf(a5, inv, bB.y);
    float o6 = fmaf(a6, inv, bB.z), o7 = fmaf(a7, inv, bB.w);
    if (RELU) {
        o0 = fmaxf(o0, 0.f); o1 = fmaxf(o1, 0.f);
        o2 = fmaxf(o2, 0.f); o3 = fmaxf(o3, 0.f);
        o4 = fmaxf(o4, 0.f); o5 = fmaxf(o5, 0.f);
        o6 = fmaxf(o6, 0.f); o7 = fmaxf(o7, 0.f);
    }
    uint4 u;
    u.x = f2bf(o0) | (f2bf(o1) << 16);
    u.y = f2bf(o2) | (f2bf(o3) << 16);
    u.z = f2bf(o4) | (f2bf(o5) << 16);
    u.w = f2bf(o6) | (f2bf(o7) << 16);
    *(uint4*)(outb + (size_t)d * HID + ch) = u;
}

// ---------------------------------------------------------------------------
// logits = aggb @ W2 + b2 (MFMA bf16, N padded to 48) ; out = log_softmax.
// C layout: row = quad*4+reg, col = nt*16+lr. Pad cols biased to -1e30.
// ---------------------------------------------------------------------------
__global__ __launch_bounds__(256) void k_final(
        const unsigned short* __restrict__ aggb,
        const unsigned short* __restrict__ W2t, const float* __restrict__ b2,
        float* __restrict__ out) {
    __shared__ float xs[64 * 44];
    int t = threadIdx.x;
    int lane = t & 63, w = t >> 6;
    int quad = lane >> 4, lr = lane & 15;
    int rowg0 = blockIdx.x * 64 + w * 16;
    int base = blockIdx.x * 64;
    int rem = N_NODES - base; if (rem > 64) rem = 64;

    bf16x8 bfr[2][3];
    #pragma unroll
    for (int kc = 0; kc < 2; ++kc)
        #pragma unroll
        for (int nt = 0; nt < 3; ++nt)
            bfr[kc][nt] = *(const bf16x8*)(W2t + (nt * 16 + lr) * HID
                                           + kc * 32 + quad * 8);
    f32x4 zero = {0.f, 0.f, 0.f, 0.f};
    f32x4 acc[3] = {zero, zero, zero};
    int arow = rowg0 + lr; if (arow >= N_NODES) arow = N_NODES - 1;
    #pragma unroll
    for (int kc = 0; kc < 2; ++kc) {
        bf16x8 af = *(const bf16x8*)(aggb + (size_t)arow * HID
                                     + kc * 32 + quad * 8);
        #pragma unroll
        for (int nt = 0; nt < 3; ++nt)
            acc[nt] = __builtin_amdgcn_mfma_f32_16x16x32_bf16(
                          af, bfr[kc][nt], acc[nt], 0, 0, 0);
    }
    float bc[3];
    #pragma unroll
    for (int nt = 0; nt < 3; ++nt) {
        int cl = nt * 16 + lr;
        bc[nt] = (cl < N_CLASS) ? b2[cl] : -1e30f;
    }
    #pragma unroll
    for (int reg = 0; reg < 4; ++reg) {
        float v0 = acc[0][reg] + bc[0];
        float v1 = acc[1][reg] + bc[1];
        float v2 = acc[2][reg] + bc[2];
        float m = fmaxf(fmaxf(v0, v1), v2);
        #pragma unroll
        for (int off = 1; off < 16; off <<= 1)
            m = fmaxf(m, __shfl_xor(m, off, 64));
        float ss = __expf(v0 - m) + __expf(v1 - m) + __expf(v2 - m);
        #pragma unroll
        for (int off = 1; off < 16; off <<= 1)
            ss += __shfl_xor(ss, off, 64);
        float lse = m + logf(ss);
        int r = w * 16 + quad * 4 + reg;
        xs[r * 44 + lr]      = v0 - lse;
        xs[r * 44 + 16 + lr] = v1 - lse;
        if (lr < 8) xs[r * 44 + 32 + lr] = v2 - lse;
    }
    __syncthreads();
    #pragma unroll
    for (int j = 0; j < 3; ++j) {
        int idx = j * 256 + t;             // float4 index, 10 per row
        if (idx < rem * 10) {
            int r = idx / 10, c4 = idx - r * 10;
            float4 v = *(const float4*)(xs + r * 44 + c4 * 4);
            *(float4*)(out + (size_t)base * N_CLASS + idx * 4) = v;
        }
    }
}

// ---------------------------------------------------------------------------
extern "C" void kernel_launch(void* const* d_in, const int* in_sizes, int n_in,
                              void* d_out, int out_size, void* d_ws, size_t ws_size,
                              hipStream_t stream) {
    const float* x     = (const float*)d_in[0];
    const int*   ei    = (const int*)  d_in[1];
    const float* W1    = (const float*)d_in[2];
    const float* b1    = (const float*)d_in[3];
    const float* Wc0   = (const float*)d_in[4];
    const float* as0   = (const float*)d_in[5];
    const float* ad0   = (const float*)d_in[6];
    const float* bias0 = (const float*)d_in[7];
    const float* Wc1   = (const float*)d_in[8];
    const float* as1   = (const float*)d_in[9];
    const float* ad1   = (const float*)d_in[10];
    const float* bias1 = (const float*)d_in[11];
    const float* W2    = (const float*)d_in[12];
    const float* b2    = (const float*)d_in[13];
    float* out = (float*)d_out;

    // Workspace (~59 MB), overlaid regions:
    // R1 (25.6 MB): buf2 (part2->part3) | then h0b bf16 [0,12.8M) -> agg1b
    //               bf16 [0,12.8M); nodeord int [12.8M, 13.2M)
    // R2 (25.6 MB): buf1 (part1->part2) | then hb bf16 @0 + agg0b bf16 @12.8M
    char* basep = (char*)d_ws;
    char* R1 = basep;
    char* R2 = basep + (size_t)N_NODES * HID * 4;
    unsigned short* h0b   = (unsigned short*)R1;
    unsigned short* agg1b = (unsigned short*)R1;
    int*            nodeord = (int*)(R1 + (size_t)N_NODES * HID * 2);
    int2*           buf2  = (int2*)R1;
    unsigned short* hb    = (unsigned short*)R2;
    unsigned short* agg0b = (unsigned short*)(R2 + (size_t)N_NODES * HID * 2);
    int2*           buf1  = (int2*)R2;

    char* mp = R2 + (size_t)N_NODES * HID * 4;
    unsigned short* Wt1  = (unsigned short*)mp;  mp += F_IN * HID * 2;
    unsigned short* Wtc0 = (unsigned short*)mp;  mp += HID * HID * 2;
    unsigned short* Wtc1 = (unsigned short*)mp;  mp += HID * HID * 2;
    unsigned short* W2t  = (unsigned short*)mp;  mp += 48 * HID * 2;
    float* as_   = (float*)mp;                   mp += N_NODES * 4;
    float* ad_   = (float*)mp;                   mp += N_NODES * 4;
    int*   col   = (int*)mp;                     mp += (size_t)ET * 4;
    int*   tail1 = (int*)mp;                     mp += NCB * 4;
    int*   fcnt  = (int*)mp;                     mp += NFB * 4;
    int*   fbase = (int*)mp;                     mp += NFB * 4;
    int*   dhist = (int*)mp;                     mp += 64 * 4;
    int*   dbase = (int*)mp;                     mp += 64 * 4;
    int*   rowptr= (int*)mp;

    const int AGG_BLOCKS = N_NODES / 32;          // 3125: 4 waves x 8 dsts
    const int NODE_BLOCKS = (N_NODES + 255) / 256;

    // ---- CSR build + degree sort (once) + weight prep ----
    hipMemsetAsync(tail1, 0, (NCB + 2 * NFB + 128) * sizeof(int), stream);
    k_prepw<<<1, 256, 0, stream>>>(W1, Wc0, Wc1, W2, Wt1, Wtc0, Wtc1, W2t);
    k_part1<<<NT1, 256, 0, stream>>>(ei, tail1, buf1);
    k_part2<<<NCB * BPC, 256, 0, stream>>>(buf1, tail1, fcnt, buf2);
    k_fscan<<<1, 1024, 0, stream>>>(fcnt, fbase, rowptr);
    k_part3<<<NFB, 256, 0, stream>>>(buf2, fcnt, fbase, rowptr, col);
    k_dhist<<<NODE_BLOCKS, 256, 0, stream>>>(rowptr, dhist);
    k_dscan<<<1, 64, 0, stream>>>(dhist, dbase);
    k_dscatter<<<NODE_BLOCKS, 256, 0, stream>>>(rowptr, dbase, nodeord);

    // h0 = relu(x@W1+b1) -> h0b (bf16; buf2 dead)
    k_lin1<<<ROW_BLOCKS, 256, 0, stream>>>(x, Wt1, b1, h0b);

    // ---- GAT layer 0 ----
    k_gemm_att<<<ROW_BLOCKS, 256, 0, stream>>>(h0b, Wtc0, as0, ad0,
                                               hb, as_, ad_);
    k_gat_agg<true><<<AGG_BLOCKS, 256, 0, stream>>>(
        rowptr, col, hb, as_, ad_, bias0, nodeord, agg0b);

    // ---- GAT layer 1 ----
    k_gemm_att<<<ROW_BLOCKS, 256, 0, stream>>>(agg0b, Wtc1, as1, ad1,
                                               hb, as_, ad_);
    k_gat_agg<false><<<AGG_BLOCKS, 256, 0, stream>>>(
        rowptr, col, hb, as_, ad_, bias1, nodeord, agg1b);

    // logits + log_softmax (MFMA)
    k_final<<<ROW_BLOCKS, 256, 0, stream>>>(agg1b, W2t, b2, out);
}

// Round 10
// 319.410 us; speedup vs baseline: 2.7796x; 2.7796x over previous
//
#include <hip/hip_runtime.h>

#define N_NODES 100000
#define N_EDGES 1600000
#define F_IN    128
#define HID     64
#define N_CLASS 40
#define NEG_SLOPE 0.2f
#define ET (N_EDGES + N_NODES)          // 1,700,000
#define ROW_BLOCKS ((N_NODES + 63) / 64)

// ---- 2-level radix partition geometry ----
#define NCB   7
#define CAP1  294912
#define BPC   144
#define NFB   782
#define CAPF  2624
#define NT1   ((ET + 2047) / 2048)

typedef __attribute__((ext_vector_type(8))) short bf16x8;
typedef __attribute__((ext_vector_type(4))) float f32x4;

__device__ __forceinline__ unsigned int f2bf(float f) {  // fp32 -> bf16 (RNE)
    unsigned int u = __float_as_uint(f);
    return (u + 0x7fffu + ((u >> 16) & 1u)) >> 16;
}

// ---------------------------------------------------------------------------
// Weight prep: bf16 transposed [n][k] so MFMA B-frags are contiguous 16 B.
// ---------------------------------------------------------------------------
__global__ __launch_bounds__(256) void k_prepw(const float* __restrict__ W1,
        const float* __restrict__ Wc0, const float* __restrict__ Wc1,
        const float* __restrict__ W2,
        unsigned short* __restrict__ Wt1, unsigned short* __restrict__ Wtc0,
        unsigned short* __restrict__ Wtc1, unsigned short* __restrict__ W2t) {
    int t = threadIdx.x;
    for (int i = t; i < F_IN * HID; i += 256) {
        int k = i >> 6, n = i & 63;
        Wt1[n * F_IN + k] = (unsigned short)f2bf(W1[i]);
    }
    for (int i = t; i < HID * HID; i += 256) {
        int k = i >> 6, n = i & 63;
        Wtc0[n * HID + k] = (unsigned short)f2bf(Wc0[i]);
        Wtc1[n * HID + k] = (unsigned short)f2bf(Wc1[i]);
    }
    for (int i = t; i < 48 * HID; i += 256) {
        int n = i >> 6, k = i & 63;
        W2t[n * HID + k] = (n < N_CLASS)
            ? (unsigned short)f2bf(W2[k * N_CLASS + n]) : (unsigned short)0;
    }
}

// ---------------------------------------------------------------------------
// h0 = relu(x @ W1 + b1) via MFMA 16x16x32 bf16. Block = 4 waves = 64 rows.
// ---------------------------------------------------------------------------
__global__ __launch_bounds__(256) void k_lin1(const float* __restrict__ x,
        const unsigned short* __restrict__ Wt1, const float* __restrict__ b1,
        unsigned short* __restrict__ h0b) {
    __shared__ float xs[4][16 * 68];
    int t = threadIdx.x;
    int lane = t & 63, w = t >> 6;
    int quad = lane >> 4, lr = lane & 15;
    int rowg0 = blockIdx.x * 64 + w * 16;

    bf16x8 bfr[4][4];                       // [kc][nt]
    #pragma unroll
    for (int kc = 0; kc < 4; ++kc)
        #pragma unroll
        for (int nt = 0; nt < 4; ++nt)
            bfr[kc][nt] = *(const bf16x8*)(Wt1 + (nt * 16 + lr) * F_IN
                                           + kc * 32 + quad * 8);
    f32x4 zero = {0.f, 0.f, 0.f, 0.f};
    f32x4 acc[4] = {zero, zero, zero, zero};

    int arow = rowg0 + lr; if (arow >= N_NODES) arow = N_NODES - 1;
    const float* ab = x + (size_t)arow * F_IN;
    #pragma unroll
    for (int kc = 0; kc < 4; ++kc) {
        const float* ap = ab + kc * 32 + quad * 8;
        float4 a0 = *(const float4*)ap;
        float4 a1 = *(const float4*)(ap + 4);
        union { bf16x8 v; unsigned int u[4]; } af;
        af.u[0] = f2bf(a0.x) | (f2bf(a0.y) << 16);
        af.u[1] = f2bf(a0.z) | (f2bf(a0.w) << 16);
        af.u[2] = f2bf(a1.x) | (f2bf(a1.y) << 16);
        af.u[3] = f2bf(a1.z) | (f2bf(a1.w) << 16);
        #pragma unroll
        for (int nt = 0; nt < 4; ++nt)
            acc[nt] = __builtin_amdgcn_mfma_f32_16x16x32_bf16(
                          af.v, bfr[kc][nt], acc[nt], 0, 0, 0);
    }
    #pragma unroll
    for (int nt = 0; nt < 4; ++nt) {
        float bv = b1[nt * 16 + lr];
        #pragma unroll
        for (int reg = 0; reg < 4; ++reg)
            xs[w][(quad * 4 + reg) * 68 + nt * 16 + lr] =
                fmaxf(acc[nt][reg] + bv, 0.f);
    }
    __syncthreads();
    #pragma unroll
    for (int j = 0; j < 2; ++j) {
        int task = j * 64 + lane;           // 16 rows x 8 col-groups
        int r = task >> 3, g = task & 7;
        int grow = blockIdx.x * 64 + w * 16 + r;
        if (grow < N_NODES) {
            const float* p = xs[w] + r * 68 + g * 8;
            uint4 u;
            u.x = f2bf(p[0]) | (f2bf(p[1]) << 16);
            u.y = f2bf(p[2]) | (f2bf(p[3]) << 16);
            u.z = f2bf(p[4]) | (f2bf(p[5]) << 16);
            u.w = f2bf(p[6]) | (f2bf(p[7]) << 16);
            *(uint4*)(h0b + (size_t)grow * HID + g * 8) = u;
        }
    }
}

// ---------------------------------------------------------------------------
// h = hin @ Wc (MFMA, bf16 in/out) ; as_ = h@att_src ; ad_ = h@att_dst.
// ---------------------------------------------------------------------------
__global__ __launch_bounds__(256) void k_gemm_att(
        const unsigned short* __restrict__ hin,
        const unsigned short* __restrict__ Wt,
        const float* __restrict__ att_s, const float* __restrict__ att_d,
        unsigned short* __restrict__ hb, float* __restrict__ as_,
        float* __restrict__ ad_) {
    __shared__ float xs[4][16 * 68];
    int t = threadIdx.x;
    int lane = t & 63, w = t >> 6;
    int quad = lane >> 4, lr = lane & 15;
    int rowg0 = blockIdx.x * 64 + w * 16;

    bf16x8 bfr[2][4];
    #pragma unroll
    for (int kc = 0; kc < 2; ++kc)
        #pragma unroll
        for (int nt = 0; nt < 4; ++nt)
            bfr[kc][nt] = *(const bf16x8*)(Wt + (nt * 16 + lr) * HID
                                           + kc * 32 + quad * 8);
    f32x4 zero = {0.f, 0.f, 0.f, 0.f};
    f32x4 acc[4] = {zero, zero, zero, zero};

    int arow = rowg0 + lr; if (arow >= N_NODES) arow = N_NODES - 1;
    #pragma unroll
    for (int kc = 0; kc < 2; ++kc) {
        bf16x8 af = *(const bf16x8*)(hin + (size_t)arow * HID
                                     + kc * 32 + quad * 8);
        #pragma unroll
        for (int nt = 0; nt < 4; ++nt)
            acc[nt] = __builtin_amdgcn_mfma_f32_16x16x32_bf16(
                          af, bfr[kc][nt], acc[nt], 0, 0, 0);
    }
    float asv[4], adv[4];
    #pragma unroll
    for (int nt = 0; nt < 4; ++nt) {
        asv[nt] = att_s[nt * 16 + lr];
        adv[nt] = att_d[nt * 16 + lr];
    }
    #pragma unroll
    for (int reg = 0; reg < 4; ++reg) {
        float p1 = acc[0][reg] * asv[0] + acc[1][reg] * asv[1]
                 + acc[2][reg] * asv[2] + acc[3][reg] * asv[3];
        float p2 = acc[0][reg] * adv[0] + acc[1][reg] * adv[1]
                 + acc[2][reg] * adv[2] + acc[3][reg] * adv[3];
        #pragma unroll
        for (int off = 1; off < 16; off <<= 1) {
            p1 += __shfl_xor(p1, off, 64);
            p2 += __shfl_xor(p2, off, 64);
        }
        if (lr == 0) {
            int grow = rowg0 + quad * 4 + reg;
            if (grow < N_NODES) { as_[grow] = p1; ad_[grow] = p2; }
        }
    }
    #pragma unroll
    for (int nt = 0; nt < 4; ++nt)
        #pragma unroll
        for (int reg = 0; reg < 4; ++reg)
            xs[w][(quad * 4 + reg) * 68 + nt * 16 + lr] = acc[nt][reg];
    __syncthreads();
    #pragma unroll
    for (int j = 0; j < 2; ++j) {
        int task = j * 64 + lane;
        int r = task >> 3, g = task & 7;
        int grow = blockIdx.x * 64 + w * 16 + r;
        if (grow < N_NODES) {
            const float* p = xs[w] + r * 68 + g * 8;
            uint4 u;
            u.x = f2bf(p[0]) | (f2bf(p[1]) << 16);
            u.y = f2bf(p[2]) | (f2bf(p[3]) << 16);
            u.z = f2bf(p[4]) | (f2bf(p[5]) << 16);
            u.w = f2bf(p[6]) | (f2bf(p[7]) << 16);
            *(uint4*)(hb + (size_t)grow * HID + g * 8) = u;
        }
    }
}

// ---------------------------------------------------------------------------
// Partition level 1: edges -> 7 coarse buckets (dst>>14).
// ---------------------------------------------------------------------------
__global__ __launch_bounds__(256) void k_part1(const int* __restrict__ ei,
        int* __restrict__ tail1, int2* __restrict__ buf1) {
    __shared__ int2 eb[2048];
    __shared__ int hist[NCB], lbase[NCB], loff[NCB], goff[NCB];
    int t = threadIdx.x;
    int tileBase = blockIdx.x * 2048;
    int total = ET - tileBase; if (total > 2048) total = 2048;
    if (t < NCB) hist[t] = 0;
    __syncthreads();

    int sr[8], dr[8];
    #pragma unroll
    for (int r = 0; r < 8; ++r) {
        int i = tileBase + r * 256 + t;
        int s = -1, d = -1;
        if (i < ET) {
            if (i < N_EDGES) { s = ei[i]; d = ei[N_EDGES + i]; }
            else             { s = d = i - N_EDGES; }
            atomicAdd(&hist[d >> 14], 1);
        }
        sr[r] = s; dr[r] = d;
    }
    __syncthreads();
    if (t == 0) {
        int run = 0;
        for (int b = 0; b < NCB; ++b) { lbase[b] = run; loff[b] = 0; run += hist[b]; }
    }
    __syncthreads();
    if (t < NCB && hist[t] > 0) goff[t] = atomicAdd(&tail1[t], hist[t]);
    #pragma unroll
    for (int r = 0; r < 8; ++r) {
        if (dr[r] >= 0) {
            int b = dr[r] >> 14;
            int p = lbase[b] + atomicAdd(&loff[b], 1);
            eb[p] = make_int2(sr[r], dr[r]);
        }
    }
    __syncthreads();
    for (int j = t; j < total; j += 256) {
        int2 e = eb[j];
        int b = e.y >> 14;
        buf1[(size_t)b * CAP1 + goff[b] + (j - lbase[b])] = e;
    }
}

// ---------------------------------------------------------------------------
// Partition level 2: coarse bucket -> 128 fine buckets (128-dst ranges).
// ---------------------------------------------------------------------------
__global__ __launch_bounds__(256) void k_part2(const int2* __restrict__ buf1,
        const int* __restrict__ tail1, int* __restrict__ fcnt,
        int2* __restrict__ buf2) {
    __shared__ int2 eb[2048];
    __shared__ int hist[128], lbase[128], loff[128], goff[128], sc[128];
    int t = threadIdx.x;
    int cb   = blockIdx.x / BPC;
    int tile = blockIdx.x % BPC;
    int n1 = tail1[cb];
    int base = tile * 2048;
    if (base >= n1) return;
    int total = n1 - base; if (total > 2048) total = 2048;
    if (t < 128) hist[t] = 0;
    __syncthreads();

    int sr[8], dr[8];
    #pragma unroll
    for (int r = 0; r < 8; ++r) {
        int i = base + r * 256 + t;
        int s = -1, d = -1;
        if (i < n1) {
            int2 e = buf1[(size_t)cb * CAP1 + i];
            s = e.x; d = e.y;
            atomicAdd(&hist[(d >> 7) & 127], 1);
        }
        sr[r] = s; dr[r] = d;
    }
    __syncthreads();
    if (t < 128) sc[t] = hist[t];
    __syncthreads();
    for (int off = 1; off < 128; off <<= 1) {
        int u = (t < 128 && t >= off) ? sc[t - off] : 0;
        __syncthreads();
        if (t < 128) sc[t] += u;
        __syncthreads();
    }
    if (t < 128) { lbase[t] = sc[t] - hist[t]; loff[t] = 0; }
    __syncthreads();
    if (t < 128 && hist[t] > 0)
        goff[t] = atomicAdd(&fcnt[cb * 128 + t], hist[t]);
    #pragma unroll
    for (int r = 0; r < 8; ++r) {
        if (dr[r] >= 0) {
            int f = (dr[r] >> 7) & 127;
            int p = lbase[f] + atomicAdd(&loff[f], 1);
            eb[p] = make_int2(sr[r], dr[r]);
        }
    }
    __syncthreads();
    for (int j = t; j < total; j += 256) {
        int2 e = eb[j];
        int f = (e.y >> 7) & 127;
        buf2[(size_t)(e.y >> 7) * CAPF + goff[f] + (j - lbase[f])] = e;
    }
}

// ---------------------------------------------------------------------------
__global__ __launch_bounds__(1024) void k_fscan(const int* __restrict__ fcnt,
        int* __restrict__ fbase, int* __restrict__ rowptr) {
    __shared__ int s[1024];
    int t = threadIdx.x;
    int v = (t < NFB) ? fcnt[t] : 0;
    s[t] = v;
    __syncthreads();
    for (int off = 1; off < 1024; off <<= 1) {
        int u = (t >= off) ? s[t - off] : 0;
        __syncthreads();
        s[t] += u;
        __syncthreads();
    }
    if (t < NFB) fbase[t] = s[t] - v;
    if (t == 0) rowptr[N_NODES] = ET;
}

// ---------------------------------------------------------------------------
// Partition level 3: fine bucket -> exact per-node CSR.
// ---------------------------------------------------------------------------
__global__ __launch_bounds__(256) void k_part3(const int2* __restrict__ buf2,
        const int* __restrict__ fcnt, const int* __restrict__ fbase,
        int* __restrict__ rowptr, int* __restrict__ col) {
    __shared__ int2 eb[CAPF];
    __shared__ int cs[CAPF];
    __shared__ int hist[128], lbase[128], loff[128], sc[128];
    int t = threadIdx.x;
    int fb = blockIdx.x;
    int nF = fcnt[fb];
    int gb = fbase[fb];
    int dbase = fb * 128;
    if (t < 128) hist[t] = 0;
    __syncthreads();
    for (int j = t; j < nF; j += 256) {
        int2 e = buf2[(size_t)fb * CAPF + j];
        eb[j] = e;
        atomicAdd(&hist[e.y - dbase], 1);
    }
    __syncthreads();
    if (t < 128) sc[t] = hist[t];
    __syncthreads();
    for (int off = 1; off < 128; off <<= 1) {
        int u = (t < 128 && t >= off) ? sc[t - off] : 0;
        __syncthreads();
        if (t < 128) sc[t] += u;
        __syncthreads();
    }
    if (t < 128) { lbase[t] = sc[t] - hist[t]; loff[t] = 0; }
    __syncthreads();
    if (t < 128 && dbase + t < N_NODES) rowptr[dbase + t] = gb + lbase[t];
    for (int j = t; j < nF; j += 256) {
        int2 e = eb[j];
        int r = e.y - dbase;
        int p = lbase[r] + atomicAdd(&loff[r], 1);
        cs[p] = e.x;
    }
    __syncthreads();
    for (int j = t; j < nF; j += 256) col[gb + j] = cs[j];
}

// ---------------------------------------------------------------------------
// Degree bucket-sort, LDS-staged (round-9's global-atomic version hit
// same-address contention: 100k atomics on 64 counters = 292 us. Per-block
// LDS hist + 1 global atomic per bucket per block fixes it.)
// ---------------------------------------------------------------------------
__global__ __launch_bounds__(256) void k_dhist(const int* __restrict__ rowptr,
        int* __restrict__ dhist) {
    __shared__ int lh[64];
    int t = threadIdx.x;
    if (t < 64) lh[t] = 0;
    __syncthreads();
    int i = blockIdx.x * 256 + t;
    if (i < N_NODES) {
        int deg = rowptr[i + 1] - rowptr[i];
        if (deg > 63) deg = 63;
        atomicAdd(&lh[deg], 1);
    }
    __syncthreads();
    if (t < 64 && lh[t] > 0) atomicAdd(&dhist[t], lh[t]);
}

__global__ __launch_bounds__(64) void k_dscan(const int* __restrict__ dhist,
        int* __restrict__ dbase) {
    int t = threadIdx.x;
    int v = dhist[t];
    int s = v;
    #pragma unroll
    for (int off = 1; off < 64; off <<= 1) {
        int u = __shfl_up(s, off, 64);
        if (t >= off) s += u;
    }
    dbase[t] = s - v;   // exclusive
}

__global__ __launch_bounds__(256) void k_dscatter(const int* __restrict__ rowptr,
        int* __restrict__ dbase, int* __restrict__ nodeord) {
    __shared__ int lh[64], goff[64];
    int t = threadIdx.x;
    if (t < 64) lh[t] = 0;
    __syncthreads();
    int i = blockIdx.x * 256 + t;
    int deg = -1, lrank = 0;
    if (i < N_NODES) {
        deg = rowptr[i + 1] - rowptr[i];
        if (deg > 63) deg = 63;
        lrank = atomicAdd(&lh[deg], 1);     // local rank within block bucket
    }
    __syncthreads();
    if (t < 64) goff[t] = (lh[t] > 0) ? atomicAdd(&dbase[t], lh[t]) : 0;
    __syncthreads();
    if (deg >= 0) nodeord[goff[deg] + lrank] = i;
}

// ---------------------------------------------------------------------------
// Fused GAT aggregate: 8 lanes per dst, 8 dsts per wave (degree-sorted so
// groups stay in lockstep). Lane holds 8 channels; NO cross-lane reduce.
// ---------------------------------------------------------------------------
template <bool RELU>
__global__ __launch_bounds__(256) void k_gat_agg(const int* __restrict__ rowptr,
        const int* __restrict__ col, const unsigned short* __restrict__ hb,
        const float* __restrict__ as_, const float* __restrict__ ad_,
        const float* __restrict__ bias, const int* __restrict__ nodeord,
        unsigned short* __restrict__ outb) {
    int t = threadIdx.x;
    int lane = t & 63;
    int wid = blockIdx.x * 4 + (t >> 6);
    int l8 = lane & 7;
    int ch = l8 * 8;
    int d = nodeord[wid * 8 + (lane >> 3)];
    int beg = rowptr[d];
    int deg = rowptr[d + 1] - beg;
    float add = ad_[d];
    int degw = deg;
    degw = max(degw, __shfl_xor(degw, 8, 64));
    degw = max(degw, __shfl_xor(degw, 16, 64));
    degw = max(degw, __shfl_xor(degw, 32, 64));

    float a0=0.f,a1=0.f,a2=0.f,a3=0.f,a4=0.f,a5=0.f,a6=0.f,a7=0.f,den=0.f;
    const unsigned short* hch = hb + ch;
    for (int c = 0; c < degw; c += 8) {
        int idx = c + l8;
        int sj = 0; float wj = 0.f;
        if (idx < deg) {
            sj = col[beg + idx];
            float e = as_[sj] + add;
            e = (e > 0.f) ? e : NEG_SLOPE * e;
            wj = __expf(e);
        }
        #pragma unroll
        for (int j = 0; j < 8; ++j) {
            int sl = (lane & 56) | j;
            int   s  = __shfl(sj, sl, 64);
            float w0 = __shfl(wj, sl, 64);   // 0 for padded slots
            den += w0;
            uint4 hv = *(const uint4*)(hch + (size_t)s * HID);
            a0 = fmaf(w0, __uint_as_float(hv.x << 16),         a0);
            a1 = fmaf(w0, __uint_as_float(hv.x & 0xffff0000u), a1);
            a2 = fmaf(w0, __uint_as_float(hv.y << 16),         a2);
            a3 = fmaf(w0, __uint_as_float(hv.y & 0xffff0000u), a3);
            a4 = fmaf(w0, __uint_as_float(hv.z << 16),         a4);
            a5 = fmaf(w0, __uint_as_float(hv.z & 0xffff0000u), a5);
            a6 = fmaf(w0, __uint_as_float(hv.w << 16),         a6);
            a7 = fmaf(w0, __uint_as_float(hv.w & 0xffff0000u), a7);
        }
    }
    float inv = 1.f / (den + 1e-16f);
    float4 bA = *(const float4*)(bias + ch);
    float4 bB = *(const float4*)(bias + ch + 4);
    float o0 = fmaf(a0, inv, bA.x), o1 = fmaf(a1, inv, bA.y);
    float o2 = fmaf(a2, inv, bA.z), o3 = fmaf(a3, inv, bA.w);
    float o4 = fmaf(a4, inv, bB.x), o5 = fmaf(a5, inv, bB.y);
    float o6 = fmaf(a6, inv, bB.z), o7 = fmaf(a7, inv, bB.w);
    if (RELU) {
        o0 = fmaxf(o0, 0.f); o1 = fmaxf(o1, 0.f);
        o2 = fmaxf(o2, 0.f); o3 = fmaxf(o3, 0.f);
        o4 = fmaxf(o4, 0.f); o5 = fmaxf(o5, 0.f);
        o6 = fmaxf(o6, 0.f); o7 = fmaxf(o7, 0.f);
    }
    uint4 u;
    u.x = f2bf(o0) | (f2bf(o1) << 16);
    u.y = f2bf(o2) | (f2bf(o3) << 16);
    u.z = f2bf(o4) | (f2bf(o5) << 16);
    u.w = f2bf(o6) | (f2bf(o7) << 16);
    *(uint4*)(outb + (size_t)d * HID + ch) = u;
}

// ---------------------------------------------------------------------------
// logits = aggb @ W2 + b2 (MFMA bf16, N padded to 48) ; out = log_softmax.
// ---------------------------------------------------------------------------
__global__ __launch_bounds__(256) void k_final(
        const unsigned short* __restrict__ aggb,
        const unsigned short* __restrict__ W2t, const float* __restrict__ b2,
        float* __restrict__ out) {
    __shared__ float xs[64 * 44];
    int t = threadIdx.x;
    int lane = t & 63, w = t >> 6;
    int quad = lane >> 4, lr = lane & 15;
    int rowg0 = blockIdx.x * 64 + w * 16;
    int base = blockIdx.x * 64;
    int rem = N_NODES - base; if (rem > 64) rem = 64;

    bf16x8 bfr[2][3];
    #pragma unroll
    for (int kc = 0; kc < 2; ++kc)
        #pragma unroll
        for (int nt = 0; nt < 3; ++nt)
            bfr[kc][nt] = *(const bf16x8*)(W2t + (nt * 16 + lr) * HID
                                           + kc * 32 + quad * 8);
    f32x4 zero = {0.f, 0.f, 0.f, 0.f};
    f32x4 acc[3] = {zero, zero, zero};
    int arow = rowg0 + lr; if (arow >= N_NODES) arow = N_NODES - 1;
    #pragma unroll
    for (int kc = 0; kc < 2; ++kc) {
        bf16x8 af = *(const bf16x8*)(aggb + (size_t)arow * HID
                                     + kc * 32 + quad * 8);
        #pragma unroll
        for (int nt = 0; nt < 3; ++nt)
            acc[nt] = __builtin_amdgcn_mfma_f32_16x16x32_bf16(
                          af, bfr[kc][nt], acc[nt], 0, 0, 0);
    }
    float bc[3];
    #pragma unroll
    for (int nt = 0; nt < 3; ++nt) {
        int cl = nt * 16 + lr;
        bc[nt] = (cl < N_CLASS) ? b2[cl] : -1e30f;
    }
    #pragma unroll
    for (int reg = 0; reg < 4; ++reg) {
        float v0 = acc[0][reg] + bc[0];
        float v1 = acc[1][reg] + bc[1];
        float v2 = acc[2][reg] + bc[2];
        float m = fmaxf(fmaxf(v0, v1), v2);
        #pragma unroll
        for (int off = 1; off < 16; off <<= 1)
            m = fmaxf(m, __shfl_xor(m, off, 64));
        float ss = __expf(v0 - m) + __expf(v1 - m) + __expf(v2 - m);
        #pragma unroll
        for (int off = 1; off < 16; off <<= 1)
            ss += __shfl_xor(ss, off, 64);
        float lse = m + logf(ss);
        int r = w * 16 + quad * 4 + reg;
        xs[r * 44 + lr]      = v0 - lse;
        xs[r * 44 + 16 + lr] = v1 - lse;
        if (lr < 8) xs[r * 44 + 32 + lr] = v2 - lse;
    }
    __syncthreads();
    #pragma unroll
    for (int j = 0; j < 3; ++j) {
        int idx = j * 256 + t;             // float4 index, 10 per row
        if (idx < rem * 10) {
            int r = idx / 10, c4 = idx - r * 10;
            float4 v = *(const float4*)(xs + r * 44 + c4 * 4);
            *(float4*)(out + (size_t)base * N_CLASS + idx * 4) = v;
        }
    }
}

// ---------------------------------------------------------------------------
extern "C" void kernel_launch(void* const* d_in, const int* in_sizes, int n_in,
                              void* d_out, int out_size, void* d_ws, size_t ws_size,
                              hipStream_t stream) {
    const float* x     = (const float*)d_in[0];
    const int*   ei    = (const int*)  d_in[1];
    const float* W1    = (const float*)d_in[2];
    const float* b1    = (const float*)d_in[3];
    const float* Wc0   = (const float*)d_in[4];
    const float* as0   = (const float*)d_in[5];
    const float* ad0   = (const float*)d_in[6];
    const float* bias0 = (const float*)d_in[7];
    const float* Wc1   = (const float*)d_in[8];
    const float* as1   = (const float*)d_in[9];
    const float* ad1   = (const float*)d_in[10];
    const float* bias1 = (const float*)d_in[11];
    const float* W2    = (const float*)d_in[12];
    const float* b2    = (const float*)d_in[13];
    float* out = (float*)d_out;

    // Workspace (~59 MB), overlaid regions (same as r9):
    char* basep = (char*)d_ws;
    char* R1 = basep;
    char* R2 = basep + (size_t)N_NODES * HID * 4;
    unsigned short* h0b   = (unsigned short*)R1;
    unsigned short* agg1b = (unsigned short*)R1;
    int*            nodeord = (int*)(R1 + (size_t)N_NODES * HID * 2);
    int2*           buf2  = (int2*)R1;
    unsigned short* hb    = (unsigned short*)R2;
    unsigned short* agg0b = (unsigned short*)(R2 + (size_t)N_NODES * HID * 2);
    int2*           buf1  = (int2*)R2;

    char* mp = R2 + (size_t)N_NODES * HID * 4;
    unsigned short* Wt1  = (unsigned short*)mp;  mp += F_IN * HID * 2;
    unsigned short* Wtc0 = (unsigned short*)mp;  mp += HID * HID * 2;
    unsigned short* Wtc1 = (unsigned short*)mp;  mp += HID * HID * 2;
    unsigned short* W2t  = (unsigned short*)mp;  mp += 48 * HID * 2;
    float* as_   = (float*)mp;                   mp += N_NODES * 4;
    float* ad_   = (float*)mp;                   mp += N_NODES * 4;
    int*   col   = (int*)mp;                     mp += (size_t)ET * 4;
    int*   tail1 = (int*)mp;                     mp += NCB * 4;
    int*   fcnt  = (int*)mp;                     mp += NFB * 4;
    int*   fbase = (int*)mp;                     mp += NFB * 4;
    int*   dhist = (int*)mp;                     mp += 64 * 4;
    int*   dbase = (int*)mp;                     mp += 64 * 4;
    int*   rowptr= (int*)mp;

    const int AGG_BLOCKS = N_NODES / 32;          // 3125: 4 waves x 8 dsts
    const int NODE_BLOCKS = (N_NODES + 255) / 256;

    // ---- CSR build + degree sort (once) + weight prep ----
    hipMemsetAsync(tail1, 0, (NCB + 2 * NFB + 128) * sizeof(int), stream);
    k_prepw<<<1, 256, 0, stream>>>(W1, Wc0, Wc1, W2, Wt1, Wtc0, Wtc1, W2t);
    k_part1<<<NT1, 256, 0, stream>>>(ei, tail1, buf1);
    k_part2<<<NCB * BPC, 256, 0, stream>>>(buf1, tail1, fcnt, buf2);
    k_fscan<<<1, 1024, 0, stream>>>(fcnt, fbase, rowptr);
    k_part3<<<NFB, 256, 0, stream>>>(buf2, fcnt, fbase, rowptr, col);
    k_dhist<<<NODE_BLOCKS, 256, 0, stream>>>(rowptr, dhist);
    k_dscan<<<1, 64, 0, stream>>>(dhist, dbase);
    k_dscatter<<<NODE_BLOCKS, 256, 0, stream>>>(rowptr, dbase, nodeord);

    // h0 = relu(x@W1+b1) -> h0b (bf16; buf2 dead)
    k_lin1<<<ROW_BLOCKS, 256, 0, stream>>>(x, Wt1, b1, h0b);

    // ---- GAT layer 0 ----
    k_gemm_att<<<ROW_BLOCKS, 256, 0, stream>>>(h0b, Wtc0, as0, ad0,
                                               hb, as_, ad_);
    k_gat_agg<true><<<AGG_BLOCKS, 256, 0, stream>>>(
        rowptr, col, hb, as_, ad_, bias0, nodeord, agg0b);

    // ---- GAT layer 1 ----
    k_gemm_att<<<ROW_BLOCKS, 256, 0, stream>>>(agg0b, Wtc1, as1, ad1,
                                               hb, as_, ad_);
    k_gat_agg<false><<<AGG_BLOCKS, 256, 0, stream>>>(
        rowptr, col, hb, as_, ad_, bias1, nodeord, agg1b);

    // logits + log_softmax (MFMA)
    k_final<<<ROW_BLOCKS, 256, 0, stream>>>(agg1b, W2t, b2, out);
}

// Round 11
// 312.958 us; speedup vs baseline: 2.8370x; 1.0206x over previous
//
#include <hip/hip_runtime.h>

#define N_NODES 100000
#define N_EDGES 1600000
#define F_IN    128
#define HID     64
#define N_CLASS 40
#define NEG_SLOPE 0.2f
#define ET (N_EDGES + N_NODES)          // 1,700,000
#define ROW_BLOCKS ((N_NODES + 63) / 64)

// ---- 2-level radix partition geometry ----
#define NCB   7
#define CAP1  294912
#define BPC   144
#define NFB   782
#define CAPF  2624
#define NT1   ((ET + 2047) / 2048)

typedef __attribute__((ext_vector_type(8))) short bf16x8;
typedef __attribute__((ext_vector_type(4))) float f32x4;

__device__ __forceinline__ unsigned int f2bf(float f) {  // fp32 -> bf16 (RNE)
    unsigned int u = __float_as_uint(f);
    return (u + 0x7fffu + ((u >> 16) & 1u)) >> 16;
}

// ---------------------------------------------------------------------------
// Weight prep (bf16, transposed [n][k]) + zero-init of all counter arrays
// (absorbs the old hipMemsetAsync: d_ws is re-poisoned 0xAA every call).
// ---------------------------------------------------------------------------
__global__ __launch_bounds__(256) void k_prepw(const float* __restrict__ W1,
        const float* __restrict__ Wc0, const float* __restrict__ Wc1,
        const float* __restrict__ W2,
        unsigned short* __restrict__ Wt1, unsigned short* __restrict__ Wtc0,
        unsigned short* __restrict__ Wtc1, unsigned short* __restrict__ W2t,
        int* __restrict__ zbuf, int zcount) {
    int t = threadIdx.x;
    for (int i = t; i < zcount; i += 256) zbuf[i] = 0;
    for (int i = t; i < F_IN * HID; i += 256) {
        int k = i >> 6, n = i & 63;
        Wt1[n * F_IN + k] = (unsigned short)f2bf(W1[i]);
    }
    for (int i = t; i < HID * HID; i += 256) {
        int k = i >> 6, n = i & 63;
        Wtc0[n * HID + k] = (unsigned short)f2bf(Wc0[i]);
        Wtc1[n * HID + k] = (unsigned short)f2bf(Wc1[i]);
    }
    for (int i = t; i < 48 * HID; i += 256) {
        int n = i >> 6, k = i & 63;
        W2t[n * HID + k] = (n < N_CLASS)
            ? (unsigned short)f2bf(W2[k * N_CLASS + n]) : (unsigned short)0;
    }
}

// ---------------------------------------------------------------------------
// FUSED: h0 = relu(x@W1+b1); h = h0@Wc0; as_=h@as0; ad_=h@ad0; hb=bf16(h).
// h0 never touches global memory (C-layout regs -> LDS -> A-frags, all
// wave-local; no barriers needed: xs[w] is private to wave w).
// ---------------------------------------------------------------------------
__global__ __launch_bounds__(256) void k_lin1att(const float* __restrict__ x,
        const unsigned short* __restrict__ Wt1, const float* __restrict__ b1,
        const unsigned short* __restrict__ Wtc0,
        const float* __restrict__ att_s, const float* __restrict__ att_d,
        unsigned short* __restrict__ hb, float* __restrict__ as_,
        float* __restrict__ ad_) {
    __shared__ float xs[4][16 * 68];
    int t = threadIdx.x;
    int lane = t & 63, w = t >> 6;
    int quad = lane >> 4, lr = lane & 15;
    int rowg0 = blockIdx.x * 64 + w * 16;

    // ---- GEMM 1: h0 = relu(x@W1+b1), K=128 ----
    f32x4 zero = {0.f, 0.f, 0.f, 0.f};
    f32x4 acc[4] = {zero, zero, zero, zero};
    int arow = rowg0 + lr; if (arow >= N_NODES) arow = N_NODES - 1;
    const float* ab = x + (size_t)arow * F_IN;
    #pragma unroll
    for (int kc = 0; kc < 4; ++kc) {
        bf16x8 bw[4];
        #pragma unroll
        for (int nt = 0; nt < 4; ++nt)
            bw[nt] = *(const bf16x8*)(Wt1 + (nt * 16 + lr) * F_IN
                                      + kc * 32 + quad * 8);
        const float* ap = ab + kc * 32 + quad * 8;
        float4 a0 = *(const float4*)ap;
        float4 a1 = *(const float4*)(ap + 4);
        union { bf16x8 v; unsigned int u[4]; } af;
        af.u[0] = f2bf(a0.x) | (f2bf(a0.y) << 16);
        af.u[1] = f2bf(a0.z) | (f2bf(a0.w) << 16);
        af.u[2] = f2bf(a1.x) | (f2bf(a1.y) << 16);
        af.u[3] = f2bf(a1.z) | (f2bf(a1.w) << 16);
        #pragma unroll
        for (int nt = 0; nt < 4; ++nt)
            acc[nt] = __builtin_amdgcn_mfma_f32_16x16x32_bf16(
                          af.v, bw[nt], acc[nt], 0, 0, 0);
    }
    // bias+relu -> LDS (C layout row=quad*4+reg, col=nt*16+lr); wave-local
    #pragma unroll
    for (int nt = 0; nt < 4; ++nt) {
        float bv = b1[nt * 16 + lr];
        #pragma unroll
        for (int reg = 0; reg < 4; ++reg)
            xs[w][(quad * 4 + reg) * 68 + nt * 16 + lr] =
                fmaxf(acc[nt][reg] + bv, 0.f);
    }
    // ---- GEMM 2: h = h0@Wc0, K=64, A from LDS ----
    f32x4 acc2[4] = {zero, zero, zero, zero};
    #pragma unroll
    for (int kc = 0; kc < 2; ++kc) {
        bf16x8 bw[4];
        #pragma unroll
        for (int nt = 0; nt < 4; ++nt)
            bw[nt] = *(const bf16x8*)(Wtc0 + (nt * 16 + lr) * HID
                                      + kc * 32 + quad * 8);
        const float* ap = xs[w] + lr * 68 + kc * 32 + quad * 8;
        float4 a0 = *(const float4*)ap;
        float4 a1 = *(const float4*)(ap + 4);
        union { bf16x8 v; unsigned int u[4]; } af;
        af.u[0] = f2bf(a0.x) | (f2bf(a0.y) << 16);
        af.u[1] = f2bf(a0.z) | (f2bf(a0.w) << 16);
        af.u[2] = f2bf(a1.x) | (f2bf(a1.y) << 16);
        af.u[3] = f2bf(a1.z) | (f2bf(a1.w) << 16);
        #pragma unroll
        for (int nt = 0; nt < 4; ++nt)
            acc2[nt] = __builtin_amdgcn_mfma_f32_16x16x32_bf16(
                          af.v, bw[nt], acc2[nt], 0, 0, 0);
    }
    // attention dots
    float asv[4], adv[4];
    #pragma unroll
    for (int nt = 0; nt < 4; ++nt) {
        asv[nt] = att_s[nt * 16 + lr];
        adv[nt] = att_d[nt * 16 + lr];
    }
    #pragma unroll
    for (int reg = 0; reg < 4; ++reg) {
        float p1 = acc2[0][reg] * asv[0] + acc2[1][reg] * asv[1]
                 + acc2[2][reg] * asv[2] + acc2[3][reg] * asv[3];
        float p2 = acc2[0][reg] * adv[0] + acc2[1][reg] * adv[1]
                 + acc2[2][reg] * adv[2] + acc2[3][reg] * adv[3];
        #pragma unroll
        for (int off = 1; off < 16; off <<= 1) {
            p1 += __shfl_xor(p1, off, 64);
            p2 += __shfl_xor(p2, off, 64);
        }
        if (lr == 0) {
            int grow = rowg0 + quad * 4 + reg;
            if (grow < N_NODES) { as_[grow] = p1; ad_[grow] = p2; }
        }
    }
    // h -> LDS (overwrite, wave-local) -> bf16 coalesced store
    #pragma unroll
    for (int nt = 0; nt < 4; ++nt)
        #pragma unroll
        for (int reg = 0; reg < 4; ++reg)
            xs[w][(quad * 4 + reg) * 68 + nt * 16 + lr] = acc2[nt][reg];
    #pragma unroll
    for (int j = 0; j < 2; ++j) {
        int task = j * 64 + lane;
        int r = task >> 3, g = task & 7;
        int grow = rowg0 + r;
        if (grow < N_NODES) {
            const float* p = xs[w] + r * 68 + g * 8;
            uint4 u;
            u.x = f2bf(p[0]) | (f2bf(p[1]) << 16);
            u.y = f2bf(p[2]) | (f2bf(p[3]) << 16);
            u.z = f2bf(p[4]) | (f2bf(p[5]) << 16);
            u.w = f2bf(p[6]) | (f2bf(p[7]) << 16);
            *(uint4*)(hb + (size_t)grow * HID + g * 8) = u;
        }
    }
}

// ---------------------------------------------------------------------------
// h = hin @ Wc (MFMA, bf16 in/out) ; as_/ad_ att dots. (layer 1)
// ---------------------------------------------------------------------------
__global__ __launch_bounds__(256) void k_gemm_att(
        const unsigned short* __restrict__ hin,
        const unsigned short* __restrict__ Wt,
        const float* __restrict__ att_s, const float* __restrict__ att_d,
        unsigned short* __restrict__ hb, float* __restrict__ as_,
        float* __restrict__ ad_) {
    __shared__ float xs[4][16 * 68];
    int t = threadIdx.x;
    int lane = t & 63, w = t >> 6;
    int quad = lane >> 4, lr = lane & 15;
    int rowg0 = blockIdx.x * 64 + w * 16;

    bf16x8 bfr[2][4];
    #pragma unroll
    for (int kc = 0; kc < 2; ++kc)
        #pragma unroll
        for (int nt = 0; nt < 4; ++nt)
            bfr[kc][nt] = *(const bf16x8*)(Wt + (nt * 16 + lr) * HID
                                           + kc * 32 + quad * 8);
    f32x4 zero = {0.f, 0.f, 0.f, 0.f};
    f32x4 acc[4] = {zero, zero, zero, zero};

    int arow = rowg0 + lr; if (arow >= N_NODES) arow = N_NODES - 1;
    #pragma unroll
    for (int kc = 0; kc < 2; ++kc) {
        bf16x8 af = *(const bf16x8*)(hin + (size_t)arow * HID
                                     + kc * 32 + quad * 8);
        #pragma unroll
        for (int nt = 0; nt < 4; ++nt)
            acc[nt] = __builtin_amdgcn_mfma_f32_16x16x32_bf16(
                          af, bfr[kc][nt], acc[nt], 0, 0, 0);
    }
    float asv[4], adv[4];
    #pragma unroll
    for (int nt = 0; nt < 4; ++nt) {
        asv[nt] = att_s[nt * 16 + lr];
        adv[nt] = att_d[nt * 16 + lr];
    }
    #pragma unroll
    for (int reg = 0; reg < 4; ++reg) {
        float p1 = acc[0][reg] * asv[0] + acc[1][reg] * asv[1]
                 + acc[2][reg] * asv[2] + acc[3][reg] * asv[3];
        float p2 = acc[0][reg] * adv[0] + acc[1][reg] * adv[1]
                 + acc[2][reg] * adv[2] + acc[3][reg] * adv[3];
        #pragma unroll
        for (int off = 1; off < 16; off <<= 1) {
            p1 += __shfl_xor(p1, off, 64);
            p2 += __shfl_xor(p2, off, 64);
        }
        if (lr == 0) {
            int grow = rowg0 + quad * 4 + reg;
            if (grow < N_NODES) { as_[grow] = p1; ad_[grow] = p2; }
        }
    }
    #pragma unroll
    for (int nt = 0; nt < 4; ++nt)
        #pragma unroll
        for (int reg = 0; reg < 4; ++reg)
            xs[w][(quad * 4 + reg) * 68 + nt * 16 + lr] = acc[nt][reg];
    #pragma unroll
    for (int j = 0; j < 2; ++j) {
        int task = j * 64 + lane;
        int r = task >> 3, g = task & 7;
        int grow = rowg0 + r;
        if (grow < N_NODES) {
            const float* p = xs[w] + r * 68 + g * 8;
            uint4 u;
            u.x = f2bf(p[0]) | (f2bf(p[1]) << 16);
            u.y = f2bf(p[2]) | (f2bf(p[3]) << 16);
            u.z = f2bf(p[4]) | (f2bf(p[5]) << 16);
            u.w = f2bf(p[6]) | (f2bf(p[7]) << 16);
            *(uint4*)(hb + (size_t)grow * HID + g * 8) = u;
        }
    }
}

// ---------------------------------------------------------------------------
// Partition level 1: edges -> 7 coarse buckets (dst>>14).
// ---------------------------------------------------------------------------
__global__ __launch_bounds__(256) void k_part1(const int* __restrict__ ei,
        int* __restrict__ tail1, int2* __restrict__ buf1) {
    __shared__ int2 eb[2048];
    __shared__ int hist[NCB], lbase[NCB], loff[NCB], goff[NCB];
    int t = threadIdx.x;
    int tileBase = blockIdx.x * 2048;
    int total = ET - tileBase; if (total > 2048) total = 2048;
    if (t < NCB) hist[t] = 0;
    __syncthreads();

    int sr[8], dr[8];
    #pragma unroll
    for (int r = 0; r < 8; ++r) {
        int i = tileBase + r * 256 + t;
        int s = -1, d = -1;
        if (i < ET) {
            if (i < N_EDGES) { s = ei[i]; d = ei[N_EDGES + i]; }
            else             { s = d = i - N_EDGES; }
            atomicAdd(&hist[d >> 14], 1);
        }
        sr[r] = s; dr[r] = d;
    }
    __syncthreads();
    if (t == 0) {
        int run = 0;
        for (int b = 0; b < NCB; ++b) { lbase[b] = run; loff[b] = 0; run += hist[b]; }
    }
    __syncthreads();
    if (t < NCB && hist[t] > 0) goff[t] = atomicAdd(&tail1[t], hist[t]);
    #pragma unroll
    for (int r = 0; r < 8; ++r) {
        if (dr[r] >= 0) {
            int b = dr[r] >> 14;
            int p = lbase[b] + atomicAdd(&loff[b], 1);
            eb[p] = make_int2(sr[r], dr[r]);
        }
    }
    __syncthreads();
    for (int j = t; j < total; j += 256) {
        int2 e = eb[j];
        int b = e.y >> 14;
        buf1[(size_t)b * CAP1 + goff[b] + (j - lbase[b])] = e;
    }
}

// ---------------------------------------------------------------------------
// Partition level 2: coarse bucket -> 128 fine buckets (128-dst ranges).
// ---------------------------------------------------------------------------
__global__ __launch_bounds__(256) void k_part2(const int2* __restrict__ buf1,
        const int* __restrict__ tail1, int* __restrict__ fcnt,
        int2* __restrict__ buf2) {
    __shared__ int2 eb[2048];
    __shared__ int hist[128], lbase[128], loff[128], goff[128], sc[128];
    int t = threadIdx.x;
    int cb   = blockIdx.x / BPC;
    int tile = blockIdx.x % BPC;
    int n1 = tail1[cb];
    int base = tile * 2048;
    if (base >= n1) return;
    int total = n1 - base; if (total > 2048) total = 2048;
    if (t < 128) hist[t] = 0;
    __syncthreads();

    int sr[8], dr[8];
    #pragma unroll
    for (int r = 0; r < 8; ++r) {
        int i = base + r * 256 + t;
        int s = -1, d = -1;
        if (i < n1) {
            int2 e = buf1[(size_t)cb * CAP1 + i];
            s = e.x; d = e.y;
            atomicAdd(&hist[(d >> 7) & 127], 1);
        }
        sr[r] = s; dr[r] = d;
    }
    __syncthreads();
    if (t < 128) sc[t] = hist[t];
    __syncthreads();
    for (int off = 1; off < 128; off <<= 1) {
        int u = (t < 128 && t >= off) ? sc[t - off] : 0;
        __syncthreads();
        if (t < 128) sc[t] += u;
        __syncthreads();
    }
    if (t < 128) { lbase[t] = sc[t] - hist[t]; loff[t] = 0; }
    __syncthreads();
    if (t < 128 && hist[t] > 0)
        goff[t] = atomicAdd(&fcnt[cb * 128 + t], hist[t]);
    #pragma unroll
    for (int r = 0; r < 8; ++r) {
        if (dr[r] >= 0) {
            int f = (dr[r] >> 7) & 127;
            int p = lbase[f] + atomicAdd(&loff[f], 1);
            eb[p] = make_int2(sr[r], dr[r]);
        }
    }
    __syncthreads();
    for (int j = t; j < total; j += 256) {
        int2 e = eb[j];
        int f = (e.y >> 7) & 127;
        buf2[(size_t)(e.y >> 7) * CAPF + goff[f] + (j - lbase[f])] = e;
    }
}

// ---------------------------------------------------------------------------
__global__ __launch_bounds__(1024) void k_fscan(const int* __restrict__ fcnt,
        int* __restrict__ fbase, int* __restrict__ rowptr) {
    __shared__ int s[1024];
    int t = threadIdx.x;
    int v = (t < NFB) ? fcnt[t] : 0;
    s[t] = v;
    __syncthreads();
    for (int off = 1; off < 1024; off <<= 1) {
        int u = (t >= off) ? s[t - off] : 0;
        __syncthreads();
        s[t] += u;
        __syncthreads();
    }
    if (t < NFB) fbase[t] = s[t] - v;
    if (t == 0) rowptr[N_NODES] = ET;
}

// ---------------------------------------------------------------------------
// Partition level 3: fine bucket -> exact per-node CSR. Also accumulates the
// degree histogram (LDS-staged) for the degree bucket-sort -- the per-node
// degrees are already in hist[], so the old k_dhist pass is free here.
// ---------------------------------------------------------------------------
__global__ __launch_bounds__(256) void k_part3(const int2* __restrict__ buf2,
        const int* __restrict__ fcnt, const int* __restrict__ fbase,
        int* __restrict__ rowptr, int* __restrict__ col,
        int* __restrict__ dhistg) {
    __shared__ int2 eb[CAPF];
    __shared__ int cs[CAPF];
    __shared__ int hist[128], lbase[128], loff[128], sc[128], dh[64];
    int t = threadIdx.x;
    int fb = blockIdx.x;
    int nF = fcnt[fb];
    int gb = fbase[fb];
    int nbase = fb * 128;
    if (t < 128) hist[t] = 0;
    if (t >= 128 && t < 192) dh[t - 128] = 0;
    __syncthreads();
    for (int j = t; j < nF; j += 256) {
        int2 e = buf2[(size_t)fb * CAPF + j];
        eb[j] = e;
        atomicAdd(&hist[e.y - nbase], 1);
    }
    __syncthreads();
    if (t < 128) sc[t] = hist[t];
    __syncthreads();
    for (int off = 1; off < 128; off <<= 1) {
        int u = (t < 128 && t >= off) ? sc[t - off] : 0;
        __syncthreads();
        if (t < 128) sc[t] += u;
        __syncthreads();
    }
    if (t < 128) { lbase[t] = sc[t] - hist[t]; loff[t] = 0; }
    __syncthreads();
    if (t < 128 && nbase + t < N_NODES) {
        rowptr[nbase + t] = gb + lbase[t];
        int dg = hist[t]; if (dg > 63) dg = 63;
        atomicAdd(&dh[dg], 1);
    }
    for (int j = t; j < nF; j += 256) {
        int2 e = eb[j];
        int r = e.y - nbase;
        int p = lbase[r] + atomicAdd(&loff[r], 1);
        cs[p] = e.x;
    }
    __syncthreads();
    for (int j = t; j < nF; j += 256) col[gb + j] = cs[j];
    if (t < 64 && dh[t] > 0) atomicAdd(&dhistg[t], dh[t]);
}

// ---------------------------------------------------------------------------
// Degree bucket-sort: scan + LDS-staged scatter (r9's same-address global
// atomics were 292 us; LDS staging fixed it -- keep this form).
// ---------------------------------------------------------------------------
__global__ __launch_bounds__(64) void k_dscan(const int* __restrict__ dhist,
        int* __restrict__ dbase) {
    int t = threadIdx.x;
    int v = dhist[t];
    int s = v;
    #pragma unroll
    for (int off = 1; off < 64; off <<= 1) {
        int u = __shfl_up(s, off, 64);
        if (t >= off) s += u;
    }
    dbase[t] = s - v;   // exclusive
}

__global__ __launch_bounds__(256) void k_dscatter(const int* __restrict__ rowptr,
        int* __restrict__ dbase, int* __restrict__ nodeord) {
    __shared__ int lh[64], goff[64];
    int t = threadIdx.x;
    if (t < 64) lh[t] = 0;
    __syncthreads();
    int i = blockIdx.x * 256 + t;
    int deg = -1, lrank = 0;
    if (i < N_NODES) {
        deg = rowptr[i + 1] - rowptr[i];
        if (deg > 63) deg = 63;
        lrank = atomicAdd(&lh[deg], 1);
    }
    __syncthreads();
    if (t < 64) goff[t] = (lh[t] > 0) ? atomicAdd(&dbase[t], lh[t]) : 0;
    __syncthreads();
    if (deg >= 0) nodeord[goff[deg] + lrank] = i;
}

// ---------------------------------------------------------------------------
// Fused GAT aggregate: 8 lanes per dst, 8 dsts per wave (degree-sorted).
// Lane holds 8 channels; NO cross-lane reduce. (unchanged from r10)
// ---------------------------------------------------------------------------
template <bool RELU>
__global__ __launch_bounds__(256) void k_gat_agg(const int* __restrict__ rowptr,
        const int* __restrict__ col, const unsigned short* __restrict__ hb,
        const float* __restrict__ as_, const float* __restrict__ ad_,
        const float* __restrict__ bias, const int* __restrict__ nodeord,
        unsigned short* __restrict__ outb) {
    int t = threadIdx.x;
    int lane = t & 63;
    int wid = blockIdx.x * 4 + (t >> 6);
    int l8 = lane & 7;
    int ch = l8 * 8;
    int d = nodeord[wid * 8 + (lane >> 3)];
    int beg = rowptr[d];
    int deg = rowptr[d + 1] - beg;
    float add = ad_[d];
    int degw = deg;
    degw = max(degw, __shfl_xor(degw, 8, 64));
    degw = max(degw, __shfl_xor(degw, 16, 64));
    degw = max(degw, __shfl_xor(degw, 32, 64));

    float a0=0.f,a1=0.f,a2=0.f,a3=0.f,a4=0.f,a5=0.f,a6=0.f,a7=0.f,den=0.f;
    const unsigned short* hch = hb + ch;
    for (int c = 0; c < degw; c += 8) {
        int idx = c + l8;
        int sj = 0; float wj = 0.f;
        if (idx < deg) {
            sj = col[beg + idx];
            float e = as_[sj] + add;
            e = (e > 0.f) ? e : NEG_SLOPE * e;
            wj = __expf(e);
        }
        #pragma unroll
        for (int j = 0; j < 8; ++j) {
            int sl = (lane & 56) | j;
            int   s  = __shfl(sj, sl, 64);
            float w0 = __shfl(wj, sl, 64);   // 0 for padded slots
            den += w0;
            uint4 hv = *(const uint4*)(hch + (size_t)s * HID);
            a0 = fmaf(w0, __uint_as_float(hv.x << 16),         a0);
            a1 = fmaf(w0, __uint_as_float(hv.x & 0xffff0000u), a1);
            a2 = fmaf(w0, __uint_as_float(hv.y << 16),         a2);
            a3 = fmaf(w0, __uint_as_float(hv.y & 0xffff0000u), a3);
            a4 = fmaf(w0, __uint_as_float(hv.z << 16),         a4);
            a5 = fmaf(w0, __uint_as_float(hv.z & 0xffff0000u), a5);
            a6 = fmaf(w0, __uint_as_float(hv.w << 16),         a6);
            a7 = fmaf(w0, __uint_as_float(hv.w & 0xffff0000u), a7);
        }
    }
    float inv = 1.f / (den + 1e-16f);
    float4 bA = *(const float4*)(bias + ch);
    float4 bB = *(const float4*)(bias + ch + 4);
    float o0 = fmaf(a0, inv, bA.x), o1 = fmaf(a1, inv, bA.y);
    float o2 = fmaf(a2, inv, bA.z), o3 = fmaf(a3, inv, bA.w);
    float o4 = fmaf(a4, inv, bB.x), o5 = fmaf(a5, inv, bB.y);
    float o6 = fmaf(a6, inv, bB.z), o7 = fmaf(a7, inv, bB.w);
    if (RELU) {
        o0 = fmaxf(o0, 0.f); o1 = fmaxf(o1, 0.f);
        o2 = fmaxf(o2, 0.f); o3 = fmaxf(o3, 0.f);
        o4 = fmaxf(o4, 0.f); o5 = fmaxf(o5, 0.f);
        o6 = fmaxf(o6, 0.f); o7 = fmaxf(o7, 0.f);
    }
    uint4 u;
    u.x = f2bf(o0) | (f2bf(o1) << 16);
    u.y = f2bf(o2) | (f2bf(o3) << 16);
    u.z = f2bf(o4) | (f2bf(o5) << 16);
    u.w = f2bf(o6) | (f2bf(o7) << 16);
    *(uint4*)(outb + (size_t)d * HID + ch) = u;
}

// ---------------------------------------------------------------------------
// logits = aggb @ W2 + b2 (MFMA bf16, N padded to 48) ; out = log_softmax.
// ---------------------------------------------------------------------------
__global__ __launch_bounds__(256) void k_final(
        const unsigned short* __restrict__ aggb,
        const unsigned short* __restrict__ W2t, const float* __restrict__ b2,
        float* __restrict__ out) {
    __shared__ float xs[64 * 44];
    int t = threadIdx.x;
    int lane = t & 63, w = t >> 6;
    int quad = lane >> 4, lr = lane & 15;
    int rowg0 = blockIdx.x * 64 + w * 16;
    int base = blockIdx.x * 64;
    int rem = N_NODES - base; if (rem > 64) rem = 64;

    bf16x8 bfr[2][3];
    #pragma unroll
    for (int kc = 0; kc < 2; ++kc)
        #pragma unroll
        for (int nt = 0; nt < 3; ++nt)
            bfr[kc][nt] = *(const bf16x8*)(W2t + (nt * 16 + lr) * HID
                                           + kc * 32 + quad * 8);
    f32x4 zero = {0.f, 0.f, 0.f, 0.f};
    f32x4 acc[3] = {zero, zero, zero};
    int arow = rowg0 + lr; if (arow >= N_NODES) arow = N_NODES - 1;
    #pragma unroll
    for (int kc = 0; kc < 2; ++kc) {
        bf16x8 af = *(const bf16x8*)(aggb + (size_t)arow * HID
                                     + kc * 32 + quad * 8);
        #pragma unroll
        for (int nt = 0; nt < 3; ++nt)
            acc[nt] = __builtin_amdgcn_mfma_f32_16x16x32_bf16(
                          af, bfr[kc][nt], acc[nt], 0, 0, 0);
    }
    float bc[3];
    #pragma unroll
    for (int nt = 0; nt < 3; ++nt) {
        int cl = nt * 16 + lr;
        bc[nt] = (cl < N_CLASS) ? b2[cl] : -1e30f;
    }
    #pragma unroll
    for (int reg = 0; reg < 4; ++reg) {
        float v0 = acc[0][reg] + bc[0];
        float v1 = acc[1][reg] + bc[1];
        float v2 = acc[2][reg] + bc[2];
        float m = fmaxf(fmaxf(v0, v1), v2);
        #pragma unroll
        for (int off = 1; off < 16; off <<= 1)
            m = fmaxf(m, __shfl_xor(m, off, 64));
        float ss = __expf(v0 - m) + __expf(v1 - m) + __expf(v2 - m);
        #pragma unroll
        for (int off = 1; off < 16; off <<= 1)
            ss += __shfl_xor(ss, off, 64);
        float lse = m + logf(ss);
        int r = w * 16 + quad * 4 + reg;
        xs[r * 44 + lr]      = v0 - lse;
        xs[r * 44 + 16 + lr] = v1 - lse;
        if (lr < 8) xs[r * 44 + 32 + lr] = v2 - lse;
    }
    __syncthreads();
    #pragma unroll
    for (int j = 0; j < 3; ++j) {
        int idx = j * 256 + t;             // float4 index, 10 per row
        if (idx < rem * 10) {
            int r = idx / 10, c4 = idx - r * 10;
            float4 v = *(const float4*)(xs + r * 44 + c4 * 4);
            *(float4*)(out + (size_t)base * N_CLASS + idx * 4) = v;
        }
    }
}

// ---------------------------------------------------------------------------
extern "C" void kernel_launch(void* const* d_in, const int* in_sizes, int n_in,
                              void* d_out, int out_size, void* d_ws, size_t ws_size,
                              hipStream_t stream) {
    const float* x     = (const float*)d_in[0];
    const int*   ei    = (const int*)  d_in[1];
    const float* W1    = (const float*)d_in[2];
    const float* b1    = (const float*)d_in[3];
    const float* Wc0   = (const float*)d_in[4];
    const float* as0   = (const float*)d_in[5];
    const float* ad0   = (const float*)d_in[6];
    const float* bias0 = (const float*)d_in[7];
    const float* Wc1   = (const float*)d_in[8];
    const float* as1   = (const float*)d_in[9];
    const float* ad1   = (const float*)d_in[10];
    const float* bias1 = (const float*)d_in[11];
    const float* W2    = (const float*)d_in[12];
    const float* b2    = (const float*)d_in[13];
    float* out = (float*)d_out;

    // Workspace (~59 MB), overlaid regions (same layout as r10):
    char* basep = (char*)d_ws;
    char* R1 = basep;
    char* R2 = basep + (size_t)N_NODES * HID * 4;
    unsigned short* agg1b = (unsigned short*)R1;
    int*            nodeord = (int*)(R1 + (size_t)N_NODES * HID * 2);
    int2*           buf2  = (int2*)R1;
    unsigned short* hb    = (unsigned short*)R2;
    unsigned short* agg0b = (unsigned short*)(R2 + (size_t)N_NODES * HID * 2);
    int2*           buf1  = (int2*)R2;

    char* mp = R2 + (size_t)N_NODES * HID * 4;
    unsigned short* Wt1  = (unsigned short*)mp;  mp += F_IN * HID * 2;
    unsigned short* Wtc0 = (unsigned short*)mp;  mp += HID * HID * 2;
    unsigned short* Wtc1 = (unsigned short*)mp;  mp += HID * HID * 2;
    unsigned short* W2t  = (unsigned short*)mp;  mp += 48 * HID * 2;
    float* as_   = (float*)mp;                   mp += N_NODES * 4;
    float* ad_   = (float*)mp;                   mp += N_NODES * 4;
    int*   col   = (int*)mp;                     mp += (size_t)ET * 4;
    int*   tail1 = (int*)mp;                     mp += NCB * 4;
    int*   fcnt  = (int*)mp;                     mp += NFB * 4;
    int*   fbase = (int*)mp;                     mp += NFB * 4;
    int*   dhist = (int*)mp;                     mp += 64 * 4;
    int*   dbase = (int*)mp;                     mp += 64 * 4;
    int*   rowptr= (int*)mp;
    const int ZCOUNT = NCB + 2 * NFB + 128;      // tail1..dbase contiguous

    const int AGG_BLOCKS = N_NODES / 32;          // 3125: 4 waves x 8 dsts
    const int NODE_BLOCKS = (N_NODES + 255) / 256;

    // ---- prep (weights bf16-T + zero counters) + CSR build + degree sort ----
    k_prepw<<<1, 256, 0, stream>>>(W1, Wc0, Wc1, W2, Wt1, Wtc0, Wtc1, W2t,
                                   tail1, ZCOUNT);
    k_part1<<<NT1, 256, 0, stream>>>(ei, tail1, buf1);
    k_part2<<<NCB * BPC, 256, 0, stream>>>(buf1, tail1, fcnt, buf2);
    k_fscan<<<1, 1024, 0, stream>>>(fcnt, fbase, rowptr);
    k_part3<<<NFB, 256, 0, stream>>>(buf2, fcnt, fbase, rowptr, col, dhist);
    k_dscan<<<1, 64, 0, stream>>>(dhist, dbase);
    k_dscatter<<<NODE_BLOCKS, 256, 0, stream>>>(rowptr, dbase, nodeord);

    // ---- fused lin1 + GAT-0 gemm/att (h0 never hits global memory) ----
    k_lin1att<<<ROW_BLOCKS, 256, 0, stream>>>(x, Wt1, b1, Wtc0, as0, ad0,
                                              hb, as_, ad_);
    k_gat_agg<true><<<AGG_BLOCKS, 256, 0, stream>>>(
        rowptr, col, hb, as_, ad_, bias0, nodeord, agg0b);

    // ---- GAT layer 1 ----
    k_gemm_att<<<ROW_BLOCKS, 256, 0, stream>>>(agg0b, Wtc1, as1, ad1,
                                               hb, as_, ad_);
    k_gat_agg<false><<<AGG_BLOCKS, 256, 0, stream>>>(
        rowptr, col, hb, as_, ad_, bias1, nodeord, agg1b);

    // logits + log_softmax (MFMA)
    k_final<<<ROW_BLOCKS, 256, 0, stream>>>(agg1b, W2t, b2, out);
}